// Round 1
// baseline (661.619 us; speedup 1.0000x reference)
//
#include <hip/hip_runtime.h>
#include <stdint.h>

// ---------------------------------------------------------------------------
// TreeLayer: h = x @ M + x_init, M = tw^2*blockdiag + bbw*strict_block_upper,
// then per-column ActNorm + sigmoid.
// R2: 256x256-tile deep-pipelined GEMM (T2 swizzle + counted-vmcnt phase
// schedule + setprio), 512 threads / 8 waves, 128 KiB dbuf LDS, raw s_barrier
// (no vmcnt(0) drain in the main loop). Paired-jc jobs: block b does
// (jc=15-p, bm) then (jc=p, bm) -> every block weight 17, 256 blocks = 1/CU.
// prep = fused x->bf16 convert + M^T build.
// ---------------------------------------------------------------------------

#define BATCH 8192
#define DIM   4096

typedef __bf16 v8bf __attribute__((ext_vector_type(8)));
typedef float  v4f  __attribute__((ext_vector_type(4)));

__device__ __forceinline__ unsigned short f2bf(float f) {
  unsigned int u = __float_as_uint(f);
  u += 0x7fffu + ((u >> 16) & 1u);          // round-to-nearest-even
  return (unsigned short)(u >> 16);
}
__device__ __forceinline__ float bf2f(unsigned int h16) {
  return __uint_as_float(h16 << 16);
}

__device__ __forceinline__ void async_copy16(const void* g, void* l) {
  __builtin_amdgcn_global_load_lds(
      (__attribute__((address_space(1))) void*)g,
      (__attribute__((address_space(3))) void*)l, 16, 0, 0);
}

// ------------------- fused: x (fp32)->bf16  +  build M^T -------------------
// blocks [0, 16384): convert x; blocks [16384, 20480): build Mt 64x64 tiles.
__global__ __launch_bounds__(256) void prep(
    const float4* __restrict__ x, uint4* __restrict__ Xb,
    const float* __restrict__ tw, const float* __restrict__ bbw,
    unsigned short* __restrict__ Mt) {
  const int b = (int)blockIdx.x;
  const int t = (int)threadIdx.x;
  __shared__ float tile[64 * 65];
  if (b < 16384) {
    int i = b * 256 + t;
    float4 a = x[2 * i], c = x[2 * i + 1];
    uint4 o;
    o.x = (unsigned)f2bf(a.x) | ((unsigned)f2bf(a.y) << 16);
    o.y = (unsigned)f2bf(a.z) | ((unsigned)f2bf(a.w) << 16);
    o.z = (unsigned)f2bf(c.x) | ((unsigned)f2bf(c.y) << 16);
    o.w = (unsigned)f2bf(c.z) | ((unsigned)f2bf(c.w) << 16);
    Xb[i] = o;
  } else {
    const int bb = b - 16384;
    const int kt = bb & 63, nt = bb >> 6;
    const int jj = t & 63, i0 = t >> 6;
    if (kt <= nt) {
      const bool diag = (kt == nt);
      const float* S = diag ? tw : bbw;
      #pragma unroll
      for (int r = 0; r < 16; ++r) {
        int i = i0 + r * 4;                                   // k-local
        float v = S[(size_t)(kt * 64 + i) * DIM + nt * 64 + jj];
        tile[i * 65 + jj] = diag ? v * v : v;
      }
      __syncthreads();
      #pragma unroll
      for (int r = 0; r < 16; ++r) {
        int nl = i0 + r * 4;                                  // n-local
        Mt[(size_t)(nt * 64 + nl) * DIM + kt * 64 + jj] = f2bf(tile[jj * 65 + nl]);
      }
    } else {
      #pragma unroll
      for (int r = 0; r < 16; ++r) {
        int nl = i0 + r * 4;
        Mt[(size_t)(nt * 64 + nl) * DIM + kt * 64 + jj] = 0;
      }
    }
  }
}

// --------------------------- main GEMM + epilogue --------------------------
// C[8192,4096] = Xb @ M. 256x256 tile, BK=64, 8 waves (2M x 4N), per-wave
// 128x64 out = acc[8][4] of 16x16 frags. LDS: 2 x (A 32KB + B 32KB) = 128KB.
// Swizzle: within each 128B row, 16B chunk c stored at c ^ (row & 7); staging
// pre-swizzles the GLOBAL source chunk (linear LDS dest for global_load_lds).
// Pipeline per K-tile t: [issue 4 stage loads of t+1; s_waitcnt vmcnt(4);
// s_barrier] then 4 phases {ds_read subtile (+2 stage issues in ph0/ph1);
// s_barrier; setprio(1); 16 MFMA; setprio(0); s_barrier}. vmcnt never drains
// to 0 except on the last tile of a job.
__global__ __launch_bounds__(512, 2) void gemm_tree(
    const unsigned short* __restrict__ Xb,    // [8192][4096] bf16
    const unsigned short* __restrict__ Mt,    // [4096 n][4096 k] bf16 (M^T)
    const float* __restrict__ Xi,             // x_init fp32
    unsigned short* __restrict__ H,           // h out, bf16
    float* __restrict__ colsum,
    float* __restrict__ colsumsq) {
  __shared__ unsigned short As[2 * 16384];    // 2 x [256 rows][64 k] swizzled
  __shared__ unsigned short Bs[2 * 16384];    // 2 x [256 n   ][64 k] swizzled

  const int b = (int)blockIdx.x;              // 256 blocks, weight-17 each
  const int p = b >> 5;                       // pairing group 0..7
  const int bm = b & 31;                      // M-tile
  const int tid = (int)threadIdx.x;
  const int wave = tid >> 6, lane = tid & 63;
  const int wm = wave >> 2, wn = wave & 3;    // 2M x 4N wave grid
  const int lr = lane & 15, quad = lane >> 4;
  const int srow = lane >> 3;                 // row within 8-row segment
  const int scol = ((lane & 7) ^ srow) * 8;   // pre-swizzled source k-chunk

  const size_t abase = (size_t)(bm * 256 + wave * 8 + srow) * DIM + scol;

  for (int job = 0; job < 2; ++job) {
    const int jc = job ? p : 15 - p;          // heavy job first
    const int ntiles = (jc + 1) * 4;          // K-tiles of 64 (>= 4, even)
    const size_t bbase = (size_t)(jc * 256 + wave * 8 + srow) * DIM + scol;

    v4f acc[8][4];
    #pragma unroll
    for (int mi = 0; mi < 8; ++mi)
      #pragma unroll
      for (int ni = 0; ni < 4; ++ni) acc[mi][ni] = {0.f, 0.f, 0.f, 0.f};

    // prologue: stage tile 0 fully into buf0 (8 issues/thread)
    #pragma unroll
    for (int r = 0; r < 4; ++r) {
      async_copy16(Xb + abase + (size_t)(r * 64) * DIM, &As[(r * 8 + wave) * 512]);
      async_copy16(Mt + bbase + (size_t)(r * 64) * DIM, &Bs[(r * 8 + wave) * 512]);
    }

    for (int t = 0; t < ntiles; ++t) {
      const unsigned short* Ac = &As[(t & 1) * 16384];
      const unsigned short* Bc = &Bs[(t & 1) * 16384];
      const int nb = ((t + 1) & 1) * 16384;   // next-buffer base (ushort idx)
      const size_t nk = (size_t)(t + 1) * 64; // next-tile k offset
      const bool pre = (t + 1 < ntiles);

      if (pre) {                               // 4 issues, then counted wait
        #pragma unroll
        for (int r = 0; r < 2; ++r) {
          async_copy16(Xb + abase + (size_t)(r * 64) * DIM + nk,
                       &As[nb + (r * 8 + wave) * 512]);
          async_copy16(Mt + bbase + (size_t)(r * 64) * DIM + nk,
                       &Bs[nb + (r * 8 + wave) * 512]);
        }
        asm volatile("s_waitcnt vmcnt(4)" ::: "memory");  // tile t landed
      } else {
        asm volatile("s_waitcnt vmcnt(0)" ::: "memory");  // job tail drain
      }
      __builtin_amdgcn_s_barrier();            // cross-wave staging visible
      __builtin_amdgcn_sched_barrier(0);

      v8bf bfr[4][2];                          // B frags: all 4N x 2kk, held
      #pragma unroll
      for (int ni = 0; ni < 4; ++ni)
        #pragma unroll
        for (int kk = 0; kk < 2; ++kk)
          bfr[ni][kk] = *(const v8bf*)&Bc[(wn * 64 + ni * 16 + lr) * 64 +
                                          (((kk * 4 + quad) ^ (lr & 7)) * 8)];

      #pragma unroll
      for (int q = 0; q < 4; ++q) {            // 4 phases x 16 MFMA
        v8bf afr[2][2];
        #pragma unroll
        for (int m2 = 0; m2 < 2; ++m2)
          #pragma unroll
          for (int kk = 0; kk < 2; ++kk)
            afr[m2][kk] = *(const v8bf*)&Ac[(wm * 128 + (q * 2 + m2) * 16 + lr) * 64 +
                                            (((kk * 4 + quad) ^ (lr & 7)) * 8)];
        if (pre && q < 2) {                    // remaining 2+2 stage issues
          const int r = q + 2;
          async_copy16(Xb + abase + (size_t)(r * 64) * DIM + nk,
                       &As[nb + (r * 8 + wave) * 512]);
          async_copy16(Mt + bbase + (size_t)(r * 64) * DIM + nk,
                       &Bs[nb + (r * 8 + wave) * 512]);
        }
        __builtin_amdgcn_s_barrier();
        __builtin_amdgcn_sched_barrier(0);
        __builtin_amdgcn_s_setprio(1);
        #pragma unroll
        for (int kk = 0; kk < 2; ++kk)
          #pragma unroll
          for (int m2 = 0; m2 < 2; ++m2)
            #pragma unroll
            for (int ni = 0; ni < 4; ++ni)
              acc[q * 2 + m2][ni] = __builtin_amdgcn_mfma_f32_16x16x32_bf16(
                  afr[m2][kk], bfr[ni][kk], acc[q * 2 + m2][ni], 0, 0, 0);
        __builtin_amdgcn_s_setprio(0);
        __builtin_amdgcn_s_barrier();          // guards next-tile restage
        __builtin_amdgcn_sched_barrier(0);
      }
    }

    // Epilogue: h = acc + x_init; store bf16 h; per-column sum/sumsq atomics.
    // C/D layout: col = lane&15, row = quad*4 + reg  [m89/m91 verified]
    const int colT = jc * 256 + wn * 64 + lr;
    const int rowT = bm * 256 + wm * 128 + quad * 4;
    #pragma unroll
    for (int ni = 0; ni < 4; ++ni) {
      const int col = colT + ni * 16;
      float s = 0.f, sq = 0.f;
      #pragma unroll
      for (int mi = 0; mi < 8; ++mi) {
        const int row = rowT + mi * 16;
        #pragma unroll
        for (int r = 0; r < 4; ++r) {
          size_t idx = (size_t)(row + r) * DIM + col;
          float h = acc[mi][ni][r] + Xi[idx];
          H[idx] = f2bf(h);
          s += h;
          sq += h * h;
        }
      }
      // lanes l, l+16, l+32, l+48 hold the same column -> reduce over quads
      s += __shfl_xor(s, 16);  s += __shfl_xor(s, 32);
      sq += __shfl_xor(sq, 16); sq += __shfl_xor(sq, 32);
      if (quad == 0) {
        atomicAdd(&colsum[col], s);
        atomicAdd(&colsumsq[col], sq);
      }
    }
  }
}

// ------------------------- column stats -> mean/scale ----------------------
__global__ __launch_bounds__(256) void finalize_stats(
    const float* __restrict__ colsum, const float* __restrict__ colsumsq,
    float* __restrict__ mean, float* __restrict__ scale) {
  int i = blockIdx.x * 256 + threadIdx.x;
  float m = colsum[i] * (1.0f / BATCH);
  float var = fmaxf(colsumsq[i] * (1.0f / BATCH) - m * m, 0.0f);
  mean[i] = m;
  scale[i] = 1.0f / (sqrtf(var) + 1e-6f);     // (h-mean)*tree_scale^2 = (h-mean)/(std+eps)
}

// ------------------------- normalize + sigmoid -----------------------------
__global__ __launch_bounds__(256) void norm_sigmoid(
    const uint4* __restrict__ H, const float* __restrict__ mean,
    const float* __restrict__ scale, float4* __restrict__ out) {
  int i = blockIdx.x * 256 + threadIdx.x;     // 8-elem group, row-major
  int cg = (i & 511) << 3;                    // column of first element
  uint4 h = H[i];
  float4 m0 = *(const float4*)&mean[cg],  m1 = *(const float4*)&mean[cg + 4];
  float4 s0 = *(const float4*)&scale[cg], s1 = *(const float4*)&scale[cg + 4];
  float hv[8];
  hv[0] = bf2f(h.x & 0xffffu); hv[1] = bf2f(h.x >> 16);
  hv[2] = bf2f(h.y & 0xffffu); hv[3] = bf2f(h.y >> 16);
  hv[4] = bf2f(h.z & 0xffffu); hv[5] = bf2f(h.z >> 16);
  hv[6] = bf2f(h.w & 0xffffu); hv[7] = bf2f(h.w >> 16);
  float mm[8] = {m0.x, m0.y, m0.z, m0.w, m1.x, m1.y, m1.z, m1.w};
  float ss[8] = {s0.x, s0.y, s0.z, s0.w, s1.x, s1.y, s1.z, s1.w};
  #pragma unroll
  for (int j = 0; j < 8; ++j) {
    float z = (hv[j] - mm[j]) * ss[j];
    hv[j] = 1.0f / (1.0f + __expf(-z));
  }
  out[2 * i]     = make_float4(hv[0], hv[1], hv[2], hv[3]);
  out[2 * i + 1] = make_float4(hv[4], hv[5], hv[6], hv[7]);
}

// ---------------------------------------------------------------------------
extern "C" void kernel_launch(void* const* d_in, const int* in_sizes, int n_in,
                              void* d_out, int out_size, void* d_ws, size_t ws_size,
                              hipStream_t stream) {
  const float* x      = (const float*)d_in[0];
  const float* x_init = (const float*)d_in[1];
  const float* tw     = (const float*)d_in[2];
  const float* bbw    = (const float*)d_in[3];
  float* out = (float*)d_out;

  char* ws = (char*)d_ws;
  // ws layout: Xb 64MB | Mt 32MB | H 64MB | colsum/colsumsq/mean/scale 4x16KB
  unsigned short* Xb = (unsigned short*)(ws);
  unsigned short* Mt = (unsigned short*)(ws + (size_t)67108864);
  unsigned short* H  = (unsigned short*)(ws + (size_t)100663296);
  float* colsum   = (float*)(ws + (size_t)167772160);
  float* colsumsq = (float*)(ws + (size_t)167772160 + 16384);
  float* mean     = (float*)(ws + (size_t)167772160 + 32768);
  float* scale    = (float*)(ws + (size_t)167772160 + 49152);

  // ws is re-poisoned to 0xAA before every timed launch -> zero accumulators.
  hipMemsetAsync(colsum, 0, 32768, stream);

  prep<<<20480, 256, 0, stream>>>((const float4*)x, (uint4*)Xb, tw, bbw, Mt);
  gemm_tree<<<256, 512, 0, stream>>>(Xb, Mt, x_init, H, colsum, colsumsq);
  finalize_stats<<<16, 256, 0, stream>>>(colsum, colsumsq, mean, scale);
  norm_sigmoid<<<(BATCH * DIM / 8 + 255) / 256, 256, 0, stream>>>(
      (const uint4*)H, mean, scale, (float4*)out);
}